// Round 2
// baseline (299.314 us; speedup 1.0000x reference)
//
#include <hip/hip_runtime.h>

// Problem constants (match reference)
#define BATCH   8
#define LEN     2048
#define DMODEL  512
#define T_MAX   200.0f

// Kernel A: scores [B,L,L] and t_diff [B,L,L], float32.
// One block per (b,i) row; 256 threads x 8 floats = 2048 columns.
__global__ __launch_bounds__(256) void scores_tdiff_kernel(
    const float* __restrict__ t,        // [B*L]
    const float* __restrict__ ls_p,     // [1]
    const float* __restrict__ gate_p,   // [2]
    float* __restrict__ scores,
    float* __restrict__ tdiff)
{
    const int row = blockIdx.x;          // b*LEN + i
    const int b   = row >> 11;           // / LEN
    const int i   = row & (LEN - 1);
    const int j0  = threadIdx.x * 8;

    const float ti = t[row];

    // learned params (wave-uniform; scalar cost once per block)
    const float ls      = log1pf(__expf(ls_p[0]));            // softplus
    const float inv_ls2 = 1.0f / (ls * ls);
    const float l = 1.0f / (1.0f + __expf(-gate_p[0]));       // sigmoid
    const float s = 1.0f / (1.0f + __expf(-gate_p[1]));
    const float inv_s2 = 2.0f / s;                            // for 2*u
    const float invT   = 1.0f / T_MAX;

    const float* trow = t + b * LEN;
    float4 v0 = *(const float4*)(trow + j0);
    float4 v1 = *(const float4*)(trow + j0 + 4);
    float tj[8] = {v0.x, v0.y, v0.z, v0.w, v1.x, v1.y, v1.z, v1.w};

    float sc[8], td[8];
#pragma unroll
    for (int k = 0; k < 8; ++k) {
        float d  = ti - tj[k];
        float ad = fabsf(d);
        float kern = __expf(-ad * ad * inv_ls2);
        float u2 = (ad * invT - l) * inv_s2;                  // 2*(d/T-l)/s
        // 1 + tanh(u) == 2 * sigmoid(2u)
        float gate = __fdividef(2.0f, 1.0f + __expf(-u2));
        sc[k] = (j0 + k <= i) ? kern * gate : 0.0f;
        td[k] = d;
    }

    size_t off = (size_t)row * LEN + j0;
    *(float4*)(scores + off)     = make_float4(sc[0], sc[1], sc[2], sc[3]);
    *(float4*)(scores + off + 4) = make_float4(sc[4], sc[5], sc[6], sc[7]);
    *(float4*)(tdiff  + off)     = make_float4(td[0], td[1], td[2], td[3]);
    *(float4*)(tdiff  + off + 4) = make_float4(td[4], td[5], td[6], td[7]);
}

// Kernel B: embedding [B,L,DMODEL], float32. 2 rows per 256-thread block,
// 4 dims per thread (one float4 store).
__global__ __launch_bounds__(256) void embed_kernel(
    const float* __restrict__ t,        // [B*L]
    float* __restrict__ emb)
{
    const int tid = threadIdx.x;
    const int row = blockIdx.x * 2 + (tid >> 7);
    const int d0  = (tid & 127) * 4;

    const float tv = t[row];
    const float c = -9.210340371976184f * (2.0f / (float)DMODEL); // -ln(10000)*2/D

    float e[4];
#pragma unroll
    for (int k = 0; k < 4; k += 2) {
        int dim = d0 + k;
        float inv_pe = __expf(c * (float)dim);       // 10000^(-2*dim/D)
        float inv_po = __expf(c * (float)(dim + 1));
        e[k]     = sinf(tv * inv_pe);                // even dim -> sin
        e[k + 1] = cosf(tv * inv_po);                // odd dim  -> cos
    }
    *(float4*)(emb + (size_t)row * DMODEL + d0) = make_float4(e[0], e[1], e[2], e[3]);
}

extern "C" void kernel_launch(void* const* d_in, const int* in_sizes, int n_in,
                              void* d_out, int out_size, void* d_ws, size_t ws_size,
                              hipStream_t stream) {
    // inputs: [0]=event_type (int, unused), [1]=event_time (f32, B*L),
    //         [2]=length_scale_param (f32,1), [3]=gate_params (f32,2)
    const float* t      = (const float*)d_in[1];
    const float* ls_p   = (const float*)d_in[2];
    const float* gate_p = (const float*)d_in[3];

    float* out = (float*)d_out;
    const size_t n_scores = (size_t)BATCH * LEN * LEN;    // 33554432
    const size_t n_emb    = (size_t)BATCH * LEN * DMODEL; // 8388608
    float* scores = out;
    float* emb    = out + n_scores;
    float* tdiff  = out + n_scores + n_emb;

    scores_tdiff_kernel<<<BATCH * LEN, 256, 0, stream>>>(t, ls_p, gate_p, scores, tdiff);
    embed_kernel<<<BATCH * LEN / 2, 256, 0, stream>>>(t, emb);
}

// Round 3
// 295.469 us; speedup vs baseline: 1.0130x; 1.0130x over previous
//
#include <hip/hip_runtime.h>

// Problem constants (match reference)
#define BATCH   8
#define LEN     2048
#define DMODEL  512
#define T_MAX   200.0f

// Kernel A: scores [B,L,L] and t_diff [B,L,L], float32.
// One block per (b,i) row; 256 threads. Each thread handles two contiguous
// 4-col groups: [tid*4, tid*4+4) and [1024+tid*4, ...). Every float4 store is
// lane-contiguous across the wave (perfect 1KB/instr coalescing).
__global__ __launch_bounds__(256) void scores_tdiff_kernel(
    const float* __restrict__ t,        // [B*L]
    const float* __restrict__ ls_p,     // [1]
    const float* __restrict__ gate_p,   // [2]
    float* __restrict__ scores,
    float* __restrict__ tdiff)
{
    const int row = blockIdx.x;          // b*LEN + i
    const int b   = row >> 11;           // / LEN
    const int i   = row & (LEN - 1);
    const int tid = threadIdx.x;
    const int c0  = tid * 4;             // cols [0,1024)
    const int c1  = 1024 + c0;           // cols [1024,2048)

    const float ti = t[row];

    // learned params (wave-uniform)
    const float ls      = log1pf(__expf(ls_p[0]));            // softplus
    const float inv_ls2 = 1.0f / (ls * ls);
    const float l = 1.0f / (1.0f + __expf(-gate_p[0]));       // sigmoid
    const float s = 1.0f / (1.0f + __expf(-gate_p[1]));
    const float inv_s2 = 2.0f / s;                            // for 2*u
    const float invT   = 1.0f / T_MAX;

    const float* trow = t + b * LEN;
    float4 ta = *(const float4*)(trow + c0);
    float4 tb = *(const float4*)(trow + c1);
    float tj[8] = {ta.x, ta.y, ta.z, ta.w, tb.x, tb.y, tb.z, tb.w};
    int   col[8] = {c0, c0 + 1, c0 + 2, c0 + 3, c1, c1 + 1, c1 + 2, c1 + 3};

    float sc[8], td[8];
#pragma unroll
    for (int k = 0; k < 8; ++k) {
        float d  = ti - tj[k];
        float ad = fabsf(d);
        float kern = __expf(-ad * ad * inv_ls2);
        float u2 = (ad * invT - l) * inv_s2;                  // 2*(d/T-l)/s
        // 1 + tanh(u) == 2 * sigmoid(2u)
        float gate = __fdividef(2.0f, 1.0f + __expf(-u2));
        sc[k] = (col[k] <= i) ? kern * gate : 0.0f;
        td[k] = d;
    }

    size_t base = (size_t)row * LEN;
    *(float4*)(scores + base + c0) = make_float4(sc[0], sc[1], sc[2], sc[3]);
    *(float4*)(scores + base + c1) = make_float4(sc[4], sc[5], sc[6], sc[7]);
    *(float4*)(tdiff  + base + c0) = make_float4(td[0], td[1], td[2], td[3]);
    *(float4*)(tdiff  + base + c1) = make_float4(td[4], td[5], td[6], td[7]);
}

// Kernel B: embedding [B,L,DMODEL], float32. 2 rows per 256-thread block,
// 4 dims per thread (one coalesced float4 store). Fast __sinf/__cosf:
// |arg| <= 200 rad -> err ~1e-4, far under the 4.0 threshold.
__global__ __launch_bounds__(256) void embed_kernel(
    const float* __restrict__ t,        // [B*L]
    float* __restrict__ emb)
{
    const int tid = threadIdx.x;
    const int row = blockIdx.x * 2 + (tid >> 7);
    const int d0  = (tid & 127) * 4;

    const float tv = t[row];
    const float c = -9.210340371976184f * (2.0f / (float)DMODEL); // -ln(10000)*2/D

    float e[4];
#pragma unroll
    for (int k = 0; k < 4; k += 2) {
        int dim = d0 + k;
        float inv_pe = __expf(c * (float)dim);       // 10000^(-2*dim/D)
        float inv_po = __expf(c * (float)(dim + 1));
        e[k]     = __sinf(tv * inv_pe);              // even dim -> sin
        e[k + 1] = __cosf(tv * inv_po);              // odd dim  -> cos
    }
    *(float4*)(emb + (size_t)row * DMODEL + d0) = make_float4(e[0], e[1], e[2], e[3]);
}

extern "C" void kernel_launch(void* const* d_in, const int* in_sizes, int n_in,
                              void* d_out, int out_size, void* d_ws, size_t ws_size,
                              hipStream_t stream) {
    // inputs: [0]=event_type (int, unused), [1]=event_time (f32, B*L),
    //         [2]=length_scale_param (f32,1), [3]=gate_params (f32,2)
    const float* t      = (const float*)d_in[1];
    const float* ls_p   = (const float*)d_in[2];
    const float* gate_p = (const float*)d_in[3];

    float* out = (float*)d_out;
    const size_t n_scores = (size_t)BATCH * LEN * LEN;    // 33554432
    const size_t n_emb    = (size_t)BATCH * LEN * DMODEL; // 8388608
    float* scores = out;
    float* emb    = out + n_scores;
    float* tdiff  = out + n_scores + n_emb;

    scores_tdiff_kernel<<<BATCH * LEN, 256, 0, stream>>>(t, ls_p, gate_p, scores, tdiff);
    embed_kernel<<<BATCH * LEN / 2, 256, 0, stream>>>(t, emb);
}